// Round 6
// baseline (247.868 us; speedup 1.0000x reference)
//
#include <hip/hip_runtime.h>

// SparseDIA (9 static offsets) @ dense: out[r,c] = sum_k diags[k, r+off_k] * other[r+off_k, c]
// N=8192, M=4096, fp32.
//
// Round-5 post-mortem: occupancy 77%, conflicts 4x down, dur still 86us. The
// residual is the __syncthreads full vmcnt(0) drain every band -- prefetch depth
// is structurally <1 band. Round-6: T3+T4 counted-vmcnt pipeline:
//   raw s_barrier + asm s_waitcnt vmcnt(11), prefetch depth D=2.
// Per-wave vmem ledger per iter: gll chunk(1) + out store(1) + diag loads(9) = 11
// unmergeable ops; vmcnt(11) retires exactly band t+1's batch, leaves t+2's 10
// loads in flight across the barrier.
// Diags live in REGISTERS (dkA/dkB double buffer, statically indexed): removes
// all ds_read_b32 + diag ds_write sync; LDS-port floor drops ~1/3.
// Ring: 512 rows x 128 B = 64 KB; live window 320 rows + 2 chunks in flight fits
// (chunk_{t+2} slot [64t+384,448) mod 512 disjoint from band t and t+1 windows).
// Both-sides XOR col swizzle kept (64 lanes -> 64 distinct 16B slots per read).
// 512 threads (8 waves), 2 blocks/CU, grid (128,4).

#define DIA_N   8192
#define DIA_M   4096
#define M4      (DIA_M / 4)   // 1024 float4 per row
#define CB      8             // float4 cols per block (128 B stripe)
#define BR      64            // rows per band
#define HALO    128           // max |offset|
#define RING    512           // ring rows (live 320 + 3 chunk slots, power of 2)
#define NB      32            // bands per block
#define GROUP   (BR * NB)     // 2048 rows per block
#define THREADS 512

typedef float f4 __attribute__((ext_vector_type(4)));
typedef __attribute__((address_space(3))) unsigned int       lds_uint;
typedef const __attribute__((address_space(1))) unsigned int glb_uint;

__global__ __launch_bounds__(THREADS, 4) void sparse_dia_kernel(
    const float* __restrict__ diags,   // [9, N]
    const float* __restrict__ other,   // [N, M]
    float* __restrict__ out)           // [N, M]
{
    constexpr int OFF[9] = {-128, -64, -8, -1, 0, 1, 8, 64, 128};

    __shared__ f4 ring[RING][CB];      // 64 KB, rows linear (gll dest), cols XOR-swizzled

    const int tid  = threadIdx.x;
    const int gr0  = blockIdx.y * GROUP;       // first output row of this block
    const int cb4  = blockIdx.x * CB;          // first float4 column

    const int wave = tid >> 6;
    const int lane = tid & 63;
    const int lrow = lane >> 3;                // row within an 8-row gll instr
    const int lcol = lane & 7;                 // LDS col slot this lane fills
    const int scol = lcol ^ lrow;              // pre-swizzled GLOBAL source col

    const int c = tid & 7;                     // f4 col for compute
    const int i = tid >> 3;                    // band row 0..63 (1 output/thread/band)

    f4* __restrict__ out4 = (f4*)out;

    // one gll instr = 8 rows x 128 B = 1 KB, linear LDS dest (slot0 includes wave*8)
    auto gll8 = [&](int slot0, int q0) {
        int q = q0 + lrow;
        q = (q < 0) ? 0 : (q >= DIA_N ? DIA_N - 1 : q);   // clamp; diag mask kills garbage
        const float* src = other + ((size_t)q * DIA_M + (size_t)(cb4 + scol) * 4);
        __builtin_amdgcn_global_load_lds((glb_uint*)src,
            (lds_uint*)&ring[slot0][0], 16, 0, 0);
    };

    // 9 diag loads -> registers. Both paths issue EXACTLY 9 vmem loads (ledger!).
    // Branch is block+band uniform. Edge path: clamp addr, mask value to 0.
    auto load_diag = [&](int t, float (&dk)[9]) {
        const int b = gr0 + t * BR + i;
        if (gr0 + t * BR - HALO >= 0 && gr0 + t * BR + (BR - 1) + HALO < DIA_N) {
#pragma unroll
            for (int k = 0; k < 9; ++k)
                dk[k] = diags[k * DIA_N + b + OFF[k]];
        } else {
#pragma unroll
            for (int k = 0; k < 9; ++k) {
                const int q  = b + OFF[k];
                const int qc = (q < 0) ? 0 : (q >= DIA_N ? DIA_N - 1 : q);
                const float v = diags[k * DIA_N + qc];
                dk[k] = ((unsigned)q < (unsigned)DIA_N) ? v : 0.f;
            }
        }
    };

    // compute band t purely from ring LDS + register diags; 9 ds_read_b128 + store
    auto compute_store = [&](int t, const float (&dk)[9]) {
        const int L0 = t * BR + HALO + i;      // logical row (abs row - (gr0-HALO))
        f4 a = (f4){0.f, 0.f, 0.f, 0.f};
#pragma unroll
        for (int k = 0; k < 9; ++k) {
            const int s = (L0 + OFF[k]) & (RING - 1);
            a += dk[k] * ring[s][c ^ (s & 7)];
        }
        out4[(size_t)(gr0 + t * BR + i) * M4 + cb4 + c] = a;
    };

    float dkA[9], dkB[9];

    // ---- prologue: band-0 window [0,320) (5 gll/wave) + chunk_1 [320,384)
    //      (1 gll/wave) + diags for bands 0,1; then ONE full drain + barrier ----
#pragma unroll
    for (int s = 0; s < 5; ++s) {
        const int inst = wave * 5 + s;
        gll8(inst * 8, gr0 - HALO + inst * 8);
    }
    gll8(320 + wave * 8, gr0 - HALO + 320 + wave * 8);
    load_diag(0, dkA);
    load_diag(1, dkB);
    asm volatile("s_waitcnt vmcnt(0)" ::: "memory");
    __builtin_amdgcn_s_barrier();
    __builtin_amdgcn_sched_barrier(0);

    // ---- main loop: per iter issue {gll t+2, store t, diag t+2} = 11 vmem ops;
    //      vmcnt(11) retires exactly band t+1's batch (issued last iter) ----
    auto body = [&](int t, float (&dk)[9]) {
        const int Lc = t * BR + 384;                       // chunk for band t+2
        gll8((Lc & (RING - 1)) + wave * 8, gr0 - HALO + Lc + wave * 8);
        compute_store(t, dk);                              // reads dk BEFORE reload
        load_diag(t + 2, dk);                              // overwrite: same parity buf
        asm volatile("s_waitcnt vmcnt(11)" ::: "memory");  // t+1 ready; t+2 in flight
        __builtin_amdgcn_s_barrier();
        __builtin_amdgcn_sched_barrier(0);                 // rule #18: pin ds_reads after
    };

    for (int t = 0; t < NB - 2; t += 2) {   // 30 iters, static parity for dkA/dkB
        body(t,     dkA);
        body(t + 1, dkB);
    }

    // ---- tail: bands NB-2, NB-1 (no further staging) ----
    compute_store(NB - 2, dkA);
    // outstanding: [g_31, store_29, d_31 x9, store_30] -> retire first 11
    asm volatile("s_waitcnt vmcnt(1)" ::: "memory");
    __builtin_amdgcn_s_barrier();
    __builtin_amdgcn_sched_barrier(0);
    compute_store(NB - 1, dkB);
}

extern "C" void kernel_launch(void* const* d_in, const int* in_sizes, int n_in,
                              void* d_out, int out_size, void* d_ws, size_t ws_size,
                              hipStream_t stream) {
    const float* diags = (const float*)d_in[0];   // 9 * 8192 fp32
    const float* other = (const float*)d_in[1];   // 8192 * 4096 fp32
    float* out         = (float*)d_out;           // 8192 * 4096 fp32

    // 512 blocks = 2/CU (64 KB LDS each), 8 waves/block -> 16 waves/CU.
    dim3 block(THREADS, 1, 1);
    dim3 grid(M4 / CB, DIA_N / GROUP, 1);         // (128, 4)
    sparse_dia_kernel<<<grid, block, 0, stream>>>(diags, other, out);
}